// Round 1
// baseline (412.933 us; speedup 1.0000x reference)
//
#include <hip/hip_runtime.h>

typedef unsigned short u16;
typedef unsigned int u32;
typedef __attribute__((ext_vector_type(8))) __bf16 bhalf8;   // MFMA A/B operand (4 VGPRs)
typedef __attribute__((ext_vector_type(8))) u16 us8;         // 16B staging vector
typedef __attribute__((ext_vector_type(4))) float f32x4;     // MFMA C/D operand

__device__ __forceinline__ u16 bf16rne(float f) {
  u32 u = __float_as_uint(f);
  u += 0x7FFFu + ((u >> 16) & 1u);
  return (u16)(u >> 16);
}

// ---------------- cast x (fp32 -> bf16), 4 elems/thread ----------------
__global__ __launch_bounds__(256) void cast4_kernel(const float* __restrict__ in,
                                                    u16* __restrict__ out, int n) {
  int i = (blockIdx.x * 256 + threadIdx.x) * 4;
  if (i >= n) return;
  float4 f = *(const float4*)(in + i);
  u32 lo = (u32)bf16rne(f.x) | ((u32)bf16rne(f.y) << 16);
  u32 hi = (u32)bf16rne(f.z) | ((u32)bf16rne(f.w) << 16);
  *(uint2*)(out + i) = make_uint2(lo, hi);
}

// ------- transpose-cast: in fp32 [R][Cn] -> out bf16 [Cn][R] (B^T) -------
__global__ __launch_bounds__(256) void transpose_cast_kernel(const float* __restrict__ in,
                                                             u16* __restrict__ out,
                                                             int R, int Cn) {
  __shared__ float tile[32][33];
  int c0 = blockIdx.x * 32, r0 = blockIdx.y * 32;
  int tx = threadIdx.x, ty = threadIdx.y;
#pragma unroll
  for (int j = 0; j < 4; ++j)
    tile[ty + j * 8][tx] = in[(size_t)(r0 + ty + j * 8) * Cn + c0 + tx];
  __syncthreads();
#pragma unroll
  for (int j = 0; j < 4; ++j)
    out[(size_t)(c0 + ty + j * 8) * R + r0 + tx] = bf16rne(tile[tx][ty + j * 8]);
}

// ---------------- bf16 MFMA GEMM: C[M,N] = A[M,K] @ Bt[N,K]^T ----------------
// 128x128 tile, BK=64, 4 waves each 64x64 (4x4 tiles of 16x16x32 MFMA).
// MODE 0: epilogue adds b_qkv and scatters bf16 into q/k/v [B,H,T,D]
// MODE 1: epilogue adds b_out and writes fp32 [M,N]
template <int MODE>
__global__ __launch_bounds__(256, 2) void gemm_bt_kernel(
    const u16* __restrict__ A, const u16* __restrict__ Bt, const float* __restrict__ bias,
    float* __restrict__ outf, u16* __restrict__ qb, u16* __restrict__ kb, u16* __restrict__ vb,
    int Mdim, int Ndim, int Kdim) {
  // pad row stride 64->72 elems (144B): row->bank step = 4 dwords, 16 rows -> 2-way (free)
  __shared__ __align__(16) u16 lA[128 * 72];
  __shared__ __align__(16) u16 lB[128 * 72];
  const int tid = threadIdx.x;
  const int lane = tid & 63, wid = tid >> 6;
  const int col = lane & 15, quad = lane >> 4;
  const int m0 = blockIdx.y * 128, n0 = blockIdx.x * 128;
  const int wm = (wid >> 1) * 64, wn = (wid & 1) * 64;

  f32x4 acc[4][4];
#pragma unroll
  for (int i = 0; i < 4; ++i)
#pragma unroll
    for (int j = 0; j < 4; ++j) acc[i][j] = f32x4{0.f, 0.f, 0.f, 0.f};

  for (int k0 = 0; k0 < Kdim; k0 += 64) {
    const u16* Ag = A + (size_t)m0 * Kdim + k0;
    const u16* Bg = Bt + (size_t)n0 * Kdim + k0;
#pragma unroll
    for (int r = 0; r < 4; ++r) {
      int c = r * 256 + tid;
      int row = c >> 3, dc = c & 7;
      us8 av = *(const us8*)(Ag + (size_t)row * Kdim + dc * 8);
      us8 bv = *(const us8*)(Bg + (size_t)row * Kdim + dc * 8);
      *(us8*)&lA[row * 72 + dc * 8] = av;
      *(us8*)&lB[row * 72 + dc * 8] = bv;
    }
    __syncthreads();
#pragma unroll
    for (int ks = 0; ks < 2; ++ks) {
      bhalf8 af[4], bfr[4];
#pragma unroll
      for (int i = 0; i < 4; ++i) {
        af[i]  = *(const bhalf8*)&lA[(wm + i * 16 + col) * 72 + ks * 32 + quad * 8];
        bfr[i] = *(const bhalf8*)&lB[(wn + i * 16 + col) * 72 + ks * 32 + quad * 8];
      }
#pragma unroll
      for (int mt = 0; mt < 4; ++mt)
#pragma unroll
        for (int nt = 0; nt < 4; ++nt)
          acc[mt][nt] = __builtin_amdgcn_mfma_f32_16x16x32_bf16(af[mt], bfr[nt], acc[mt][nt], 0, 0, 0);
    }
    __syncthreads();
  }

  // epilogue: C/D layout row=quad*4+reg, col=lane&15 (m89/m91 verified)
  if (MODE == 0) {
#pragma unroll
    for (int nt = 0; nt < 4; ++nt) {
      int n = n0 + wn + nt * 16 + col;
      float bv = bias[n];
      int which = n >> 10, cc = n & 1023, hh = cc >> 6, dd = cc & 63;
      u16* dst = (which == 0) ? qb : ((which == 1) ? kb : vb);
#pragma unroll
      for (int mt = 0; mt < 4; ++mt)
#pragma unroll
        for (int reg = 0; reg < 4; ++reg) {
          int m = m0 + wm + mt * 16 + quad * 4 + reg;
          int bb = m >> 11, tt = m & 2047;
          dst[((size_t)((bb << 4) + hh) * 2048 + tt) * 64 + dd] = bf16rne(acc[mt][nt][reg] + bv);
        }
    }
  } else {
#pragma unroll
    for (int mt = 0; mt < 4; ++mt)
#pragma unroll
      for (int nt = 0; nt < 4; ++nt) {
        int n = n0 + wn + nt * 16 + col;
        float bv = bias[n];
#pragma unroll
        for (int reg = 0; reg < 4; ++reg) {
          int m = m0 + wm + mt * 16 + quad * 4 + reg;
          outf[(size_t)m * Ndim + n] = acc[mt][nt][reg] + bv;
        }
      }
  }
}

// ---------------- causal flash attention ----------------
// grid (T/128, B*H); 4 waves, each owns 32 q-rows. D=64.
__global__ __launch_bounds__(256, 2) void attn_kernel(const u16* __restrict__ Q,
                                                      const u16* __restrict__ K,
                                                      const u16* __restrict__ V,
                                                      u16* __restrict__ aout) {
  __shared__ __align__(16) u16 lK[128 * 72];   // K-tile [t'][d], pad 72
  __shared__ __align__(16) u16 lV[64 * 136];   // V-tile transposed [d][t'], pad 136
  __shared__ __align__(16) u16 lP[128 * 40];   // P round-trip, 32 cols/phase, pad 40
  const int tid = threadIdx.x;
  const int lane = tid & 63, wid = tid >> 6;
  const int col = lane & 15, quad = lane >> 4;
  const int qt = blockIdx.x, bh = blockIdx.y;
  const u16* Qb = Q + (size_t)bh * 2048 * 64;
  const u16* Kb = K + (size_t)bh * 2048 * 64;
  const u16* Vb = V + (size_t)bh * 2048 * 64;
  const float CS = 0.18033688011112042f;  // log2(e)/8

  // Q fragments (A-operand), loop-invariant: Q[t = base+col][d = ks*32+quad*8 ..]
  bhalf8 qf[2][2];
#pragma unroll
  for (int mt = 0; mt < 2; ++mt)
#pragma unroll
    for (int ks = 0; ks < 2; ++ks) {
      int t = qt * 128 + wid * 32 + mt * 16 + col;
      qf[mt][ks] = *(const bhalf8*)(Qb + (size_t)t * 64 + ks * 32 + quad * 8);
    }

  f32x4 oacc[2][4];
  float mrow[2][4], lrow[2][4];
#pragma unroll
  for (int mt = 0; mt < 2; ++mt)
#pragma unroll
    for (int i = 0; i < 4; ++i) {
      oacc[mt][i] = f32x4{0.f, 0.f, 0.f, 0.f};
      mrow[mt][i] = -1e30f;
      lrow[mt][i] = 0.f;
    }

  for (int kt = 0; kt <= qt; ++kt) {
    __syncthreads();  // previous tile's lK/lV consumers done
    const u16* Kg = Kb + (size_t)kt * 128 * 64;
    const u16* Vg = Vb + (size_t)kt * 128 * 64;
#pragma unroll
    for (int r = 0; r < 4; ++r) {
      int c = r * 256 + tid;
      {  // K straight copy
        int row = c >> 3, dc = c & 7;
        *(us8*)&lK[row * 72 + dc * 8] = *(const us8*)(Kg + (size_t)row * 64 + dc * 8);
      }
      {  // V transposed: chunk (t, dc) -> 8 scalar writes Vt[d][t]
        int tcol = c & 127, dc = c >> 7;
        us8 vv = *(const us8*)(Vg + (size_t)tcol * 64 + dc * 8);
#pragma unroll
        for (int j = 0; j < 8; ++j) lV[(dc * 8 + j) * 136 + tcol] = vv[j];
      }
    }
    __syncthreads();

    // S = Q K^T  (B-operand = K rows: B[k=d][n=t'])
    f32x4 sacc[2][8];
#pragma unroll
    for (int mt = 0; mt < 2; ++mt)
#pragma unroll
      for (int nt = 0; nt < 8; ++nt) sacc[mt][nt] = f32x4{0.f, 0.f, 0.f, 0.f};
#pragma unroll
    for (int ks = 0; ks < 2; ++ks) {
      bhalf8 kf[8];
#pragma unroll
      for (int nt = 0; nt < 8; ++nt)
        kf[nt] = *(const bhalf8*)&lK[(nt * 16 + col) * 72 + ks * 32 + quad * 8];
#pragma unroll
      for (int mt = 0; mt < 2; ++mt)
#pragma unroll
        for (int nt = 0; nt < 8; ++nt)
          sacc[mt][nt] = __builtin_amdgcn_mfma_f32_16x16x32_bf16(qf[mt][ks], kf[nt], sacc[mt][nt], 0, 0, 0);
    }

    if (kt == qt) {  // causal mask on the diagonal tile
#pragma unroll
      for (int mt = 0; mt < 2; ++mt)
#pragma unroll
        for (int nt = 0; nt < 8; ++nt)
#pragma unroll
          for (int reg = 0; reg < 4; ++reg) {
            int srow = wid * 32 + mt * 16 + quad * 4 + reg;
            int scol = nt * 16 + col;
            if (scol > srow) sacc[mt][nt][reg] = -1e30f;
          }
    }

    // online softmax: stats per row (row = quad*4+reg within each 16-tile)
#pragma unroll
    for (int mt = 0; mt < 2; ++mt)
#pragma unroll
      for (int reg = 0; reg < 4; ++reg) {
        float mx = sacc[mt][0][reg];
#pragma unroll
        for (int nt = 1; nt < 8; ++nt) mx = fmaxf(mx, sacc[mt][nt][reg]);
        mx = fmaxf(mx, __shfl_xor(mx, 1));
        mx = fmaxf(mx, __shfl_xor(mx, 2));
        mx = fmaxf(mx, __shfl_xor(mx, 4));
        mx = fmaxf(mx, __shfl_xor(mx, 8));
        float om = mrow[mt][reg];
        float nm = fmaxf(om, mx);
        float al = exp2f((om - nm) * CS);
        mrow[mt][reg] = nm;
        float rs = 0.f;
#pragma unroll
        for (int nt = 0; nt < 8; ++nt) {
          float p = exp2f((sacc[mt][nt][reg] - nm) * CS);
          sacc[mt][nt][reg] = p;
          rs += p;
        }
        rs += __shfl_xor(rs, 1);
        rs += __shfl_xor(rs, 2);
        rs += __shfl_xor(rs, 4);
        rs += __shfl_xor(rs, 8);
        lrow[mt][reg] = lrow[mt][reg] * al + rs;
#pragma unroll
        for (int dt = 0; dt < 4; ++dt) oacc[mt][dt][reg] *= al;
      }

    // PV in 4 phases of 32 k-cols: C-layout P -> LDS -> A-layout P (wave-private rows)
#pragma unroll
    for (int ph = 0; ph < 4; ++ph) {
#pragma unroll
      for (int mt = 0; mt < 2; ++mt)
#pragma unroll
        for (int h2 = 0; h2 < 2; ++h2) {
          int nt = ph * 2 + h2;
#pragma unroll
          for (int reg = 0; reg < 4; ++reg)
            lP[(wid * 32 + mt * 16 + quad * 4 + reg) * 40 + h2 * 16 + col] =
                bf16rne(sacc[mt][nt][reg]);
        }
      bhalf8 vf[4];
#pragma unroll
      for (int dt = 0; dt < 4; ++dt)
        vf[dt] = *(const bhalf8*)&lV[(dt * 16 + col) * 136 + ph * 32 + quad * 8];
#pragma unroll
      for (int mt = 0; mt < 2; ++mt) {
        bhalf8 pf = *(const bhalf8*)&lP[(wid * 32 + mt * 16 + col) * 40 + quad * 8];
#pragma unroll
        for (int dt = 0; dt < 4; ++dt)
          oacc[mt][dt] = __builtin_amdgcn_mfma_f32_16x16x32_bf16(pf, vf[dt], oacc[mt][dt], 0, 0, 0);
      }
    }
  }

  // epilogue: O/l -> aout [B,T,C] bf16 (C = h*64+d)
  int b = bh >> 4, h = bh & 15;
#pragma unroll
  for (int mt = 0; mt < 2; ++mt)
#pragma unroll
    for (int reg = 0; reg < 4; ++reg) {
      float inv = 1.f / lrow[mt][reg];
      int t = qt * 128 + wid * 32 + mt * 16 + quad * 4 + reg;
      size_t base = ((size_t)(b * 2048 + t)) * 1024 + h * 64;
#pragma unroll
      for (int dt = 0; dt < 4; ++dt)
        aout[base + dt * 16 + col] = bf16rne(oacc[mt][dt][reg] * inv);
    }
}

// ---------------- launch ----------------
// Workspace layout (bytes), total ~92.3 MB:
//  xb    @ 0         : 8192x1024 bf16      (16777216)
//  wqkvT @ 16777216  : 3072x1024 bf16      ( 6291456)
//  woutT @ 23068672  : 1024x1024 bf16      ( 2097152)
//  q     @ 25165824  : [B,H,T,D] bf16      (16777216)
//  k     @ 41943040  : [B,H,T,D] bf16      (16777216)
//  v     @ 58720256  : [B,H,T,D] bf16      (16777216)
//  aout  @ 75497472  : 8192x1024 bf16      (16777216)
extern "C" void kernel_launch(void* const* d_in, const int* in_sizes, int n_in,
                              void* d_out, int out_size, void* d_ws, size_t ws_size,
                              hipStream_t stream) {
  const float* x     = (const float*)d_in[0];
  const float* w_qkv = (const float*)d_in[1];
  const float* b_qkv = (const float*)d_in[2];
  const float* w_out = (const float*)d_in[3];
  const float* b_out = (const float*)d_in[4];
  float* out = (float*)d_out;
  char* ws = (char*)d_ws;
  u16* xb    = (u16*)(ws);
  u16* wqkvT = (u16*)(ws + 16777216);
  u16* woutT = (u16*)(ws + 23068672);
  u16* qb    = (u16*)(ws + 25165824);
  u16* kb    = (u16*)(ws + 41943040);
  u16* vb    = (u16*)(ws + 58720256);
  u16* ab    = (u16*)(ws + 75497472);

  cast4_kernel<<<8192, 256, 0, stream>>>(x, xb, 8388608);
  dim3 tb(32, 8);
  transpose_cast_kernel<<<dim3(96, 32), tb, 0, stream>>>(w_qkv, wqkvT, 1024, 3072);
  transpose_cast_kernel<<<dim3(32, 32), tb, 0, stream>>>(w_out, woutT, 1024, 1024);
  gemm_bt_kernel<0><<<dim3(24, 64), 256, 0, stream>>>(xb, wqkvT, b_qkv, nullptr, qb, kb, vb,
                                                      8192, 3072, 1024);
  attn_kernel<<<dim3(16, 64), 256, 0, stream>>>(qb, kb, vb, ab);
  gemm_bt_kernel<1><<<dim3(8, 64), 256, 0, stream>>>(ab, woutT, b_out, out, nullptr, nullptr,
                                                     nullptr, 8192, 1024, 1024);
}